// Round 1
// baseline (366.718 us; speedup 1.0000x reference)
//
#include <hip/hip_runtime.h>
#include <math.h>

#define NCLS 21
#define NGT 32
#define CLIPLEN 256.0f
#define MAXN 512.0f
#define FEPS 1.1920928955078125e-07f

// acc layout (doubles): 0 loss_l, 1 loss_c, 2 loss_prop_l, 3 loss_prop_c,
//                       4 loss_ct, 5 pos_count, 6 prop_pos_count

__device__ __forceinline__ float focal_term(const float* __restrict__ row, int tgt) {
    float r[NCLS];
#pragma unroll
    for (int i = 0; i < NCLS; ++i) r[i] = row[i];
    float m = r[0];
#pragma unroll
    for (int i = 1; i < NCLS; ++i) m = fmaxf(m, r[i]);
    float s = 0.0f;
    float tl = 0.0f;
#pragma unroll
    for (int i = 0; i < NCLS; ++i) {
        s += __expf(r[i] - m);
        if (i == tgt) tl = r[i];      // compile-time index, runtime select
    }
    float lse = m + __logf(s);
    float pt = __expf(tl - lse) + 1e-10f;
    float a = (tgt == 0) ? 0.25f : 0.75f;
    float om = 1.0f - pt;
    return -a * om * om * __logf(pt);
}

__global__ __launch_bounds__(256) void msl_main(
    const float* __restrict__ loc_data,
    const float* __restrict__ conf_data,
    const float* __restrict__ prop_loc_data,
    const float* __restrict__ prop_conf_data,
    const float* __restrict__ center_data,
    const float* __restrict__ priors,
    const float* __restrict__ targets,
    double* __restrict__ acc,
    int K)
{
    __shared__ float s_t0[NGT], s_t1[NGT], s_lb[NGT];
    __shared__ float s_red[7 * 4];

    const int b   = blockIdx.y;
    const int tid = threadIdx.x;
    const int k   = blockIdx.x * blockDim.x + tid;

    if (tid < NGT) {
        const float* tg = targets + ((size_t)b * NGT + tid) * 3;
        s_t0[tid] = tg[0];
        s_t1[tid] = tg[1];
        s_lb[tid] = tg[2];
    }
    __syncthreads();

    const size_t idx = (size_t)b * K + k;
    const float c = priors[k];

    // ---- match: argmin over 32 GTs (first occurrence of min) ----
    float bestA = 3.0e38f;
    int bestN = 0;
#pragma unroll
    for (int n = 0; n < NGT; ++n) {
        float l = (c - s_t0[n]) * CLIPLEN;
        float r = (s_t1[n] - c) * CLIPLEN;
        float a = (l < 0.0f || r < 0.0f) ? MAXN : (l + r);
        if (a < bestA) { bestA = a; bestN = n; }
    }
    const float t0 = s_t0[bestN];
    const float t1 = s_t1[bestN];
    const float tl = (c - t0) * CLIPLEN;   // loc_t[0]
    const float tr = (t1 - c) * CLIPLEN;   // loc_t[1]
    int conf_t = (bestA >= MAXN) ? 0 : (int)s_lb[bestN];

    // ---- per-anchor small loads ----
    const float2 loc  = ((const float2*)loc_data)[idx];
    const float2 plo  = ((const float2*)prop_loc_data)[idx];
    const float  x    = center_data[idx];
    const float pl = loc.x, pr = loc.y;

    // ---- IoU(loc_data, loc_t) ----
    const float inter = fminf(pl, tl) + fminf(pr, tr);
    const float uni   = pl + pr + tl + tr - inter;
    const float iou   = inter / fmaxf(uni, FEPS);

    const int prop_conf_t = (iou < 0.5f) ? 0 : conf_t;
    const float posf = (conf_t > 0) ? 1.0f : 0.0f;
    const float ppf  = (prop_conf_t > 0) ? 1.0f : 0.0f;

    // ---- loss_l: GIoU ----
    const float ac   = fmaxf(pl, tl) + fmaxf(pr, tr);
    const float giou = iou - (ac - uni) / fmaxf(ac, FEPS);
    const float v_ll = (1.0f - giou) * posf;

    // ---- loss_prop_l: L1 on encoded offsets ----
    const float prop_w = pl + pr;
    const float inv_hw = 1.0f / (0.5f * prop_w);
    const float plt0 = (tl - pl) * inv_hw;
    const float plt1 = (tr - pr) * inv_hw;
    const float v_lpl = (fabsf(plo.x - plt0) + fabsf(plo.y - plt1)) * ppf;

    // ---- loss_ct: BCE(center, IoU(cur_loc_p, loc_t)) ----
    const float cur0 = 0.5f * prop_w * plo.x + pl;
    const float cur1 = 0.5f * prop_w * plo.y + pr;
    const float in2  = fminf(cur0, tl) + fminf(cur1, tr);
    const float un2  = cur0 + cur1 + tl + tr - in2;
    const float iou2 = fmaxf(in2 / fmaxf(un2, FEPS), 0.0f);
    const float bce  = fmaxf(x, 0.0f) - x * iou2 + log1pf(__expf(-fabsf(x)));
    const float v_ct = bce * posf;

    // ---- focal terms (sum over ALL anchors) ----
    const float v_lc  = focal_term(conf_data      + idx * NCLS, conf_t);
    const float v_lpc = focal_term(prop_conf_data + idx * NCLS, prop_conf_t);

    // ---- block reduction ----
    float vals[7] = { v_ll, v_lc, v_lpl, v_lpc, v_ct, posf, ppf };
    const int lane = tid & 63;
    const int wave = tid >> 6;
#pragma unroll
    for (int i = 0; i < 7; ++i) {
        float v = vals[i];
#pragma unroll
        for (int off = 32; off > 0; off >>= 1) v += __shfl_xor(v, off);
        if (lane == 0) s_red[i * 4 + wave] = v;
    }
    __syncthreads();
    if (tid == 0) {
#pragma unroll
        for (int i = 0; i < 7; ++i) {
            double s = (double)s_red[i * 4 + 0] + (double)s_red[i * 4 + 1]
                     + (double)s_red[i * 4 + 2] + (double)s_red[i * 4 + 3];
            atomicAdd(&acc[i], s);
        }
    }
}

__global__ void msl_finalize(const double* __restrict__ acc, float* __restrict__ out) {
    const double N  = fmax(acc[5], 1.0);
    const double PN = fmax(acc[6], 1.0);
    out[0] = (float)(acc[0] / N);   // loss_l
    out[1] = (float)(acc[1] / N);   // loss_c
    out[2] = (float)(acc[2] / PN);  // loss_prop_l
    out[3] = (float)(acc[3] / PN);  // loss_prop_c
    out[4] = (float)(acc[4] / N);   // loss_ct
}

extern "C" void kernel_launch(void* const* d_in, const int* in_sizes, int n_in,
                              void* d_out, int out_size, void* d_ws, size_t ws_size,
                              hipStream_t stream) {
    const float* loc_data       = (const float*)d_in[0];
    const float* conf_data      = (const float*)d_in[1];
    const float* prop_loc_data  = (const float*)d_in[2];
    const float* prop_conf_data = (const float*)d_in[3];
    const float* center_data    = (const float*)d_in[4];
    const float* priors         = (const float*)d_in[5];
    const float* targets        = (const float*)d_in[6];
    float* out = (float*)d_out;

    const int K = in_sizes[5];            // priors: (K, 1)
    const int B = in_sizes[6] / (NGT * 3);

    double* acc = (double*)d_ws;
    hipMemsetAsync(acc, 0, 7 * sizeof(double), stream);

    dim3 grid(K / 256, B);
    msl_main<<<grid, 256, 0, stream>>>(loc_data, conf_data, prop_loc_data,
                                       prop_conf_data, center_data, priors,
                                       targets, acc, K);
    msl_finalize<<<1, 1, 0, stream>>>(acc, out);
}